// Round 5
// baseline (57.456 us; speedup 1.0000x reference)
//
#include <hip/hip_runtime.h>

// out[b,s,h,w] = sum_t input[b,s,t,h,w] * weight[t, h%8, w%8]   (h,w < 256; else 0)
// output[b, s*1024 + i*32 + j, q*16 + p] = out[b,s, 8i+p, 8j+q]   i,j in [0,32), p,q in [0,16)
//
// Block = (b, s, ig in 0..3, jg in 0..1): 8 window-rows x 16 window-cols.
// Region rows [64*ig, 64*ig+72) x cols [128*jg, 128*jg+136).  Halo amp 1.195x
// (was 1.33x with the (4,16) geometry).
//
// Rolling schedule (stores overlap in-flight loads; barriers don't drain stores):
//   S0: compute rows [0,24) -> LDS ; lds_barrier
//   k = 0..2:
//     issue 16 global loads/thread for rows [24+16k, 40+16k) into regs
//     store window-rows di = 2k, 2k+1  (LDS rows already committed)
//     FMA + commit regs -> LDS ; lds_barrier (lgkmcnt only -- nt stores stay in flight)
//   store window-rows di = 6, 7

namespace {

constexpr int TT   = 16;
constexpr int ROWS = 72;    // 8*8 + 8 halo
constexpr int C4   = 34;    // float4 slots per row = 136 cols
constexpr int LDSW = 140;   // row pitch (floats): float4-aligned, 2-way-max bank spread

typedef float fvec4 __attribute__((ext_vector_type(4)));

// Barrier that waits only LDS ops: in-flight nontemporal stores (and any
// loads whose consumers are register-tracked by compiler vmcnt) cross freely.
__device__ __forceinline__ void lds_barrier() {
    __builtin_amdgcn_sched_barrier(0);
    asm volatile("s_waitcnt lgkmcnt(0)" ::: "memory");
    __builtin_amdgcn_s_barrier();
    __builtin_amdgcn_sched_barrier(0);
}

__device__ __forceinline__ void store_nt(float* p, float a, float b, float c, float d) {
    fvec4 v; v.x = a; v.y = b; v.z = c; v.w = d;
    __builtin_nontemporal_store(v, reinterpret_cast<fvec4*>(p));
}

__device__ __forceinline__ bool load16(float4* v, const float* __restrict__ inp, int h, int w) {
    if (h < 256 && w < 256) {
        const float* gp = inp + h * 256 + w;
#pragma unroll
        for (int t = 0; t < TT; ++t)
            v[t] = *reinterpret_cast<const float4*>(gp + t * 65536);
        return true;
    }
    return false;
}

__device__ __forceinline__ float4 dot16(const float4* v, const float* __restrict__ wlds,
                                        int h, int w) {
    const float* wrow = &wlds[(h & 7) * 8 + (w & 7)];
    float4 acc = make_float4(0.f, 0.f, 0.f, 0.f);
#pragma unroll
    for (int t = 0; t < TT; ++t) {
        const float4 wv = *reinterpret_cast<const float4*>(wrow + t * 64);
        acc.x += v[t].x * wv.x;
        acc.y += v[t].y * wv.y;
        acc.z += v[t].z * wv.z;
        acc.w += v[t].w * wv.w;
    }
    return acc;
}

// interleaved load+fma (used for S0 where there's nothing to overlap)
__device__ __forceinline__ float4 compute_slot(
    const float* __restrict__ inp, const float* __restrict__ wlds,
    int h0, int w0, int r, int c4)
{
    const int h = h0 + r;
    const int w = w0 + c4 * 4;
    float4 acc = make_float4(0.f, 0.f, 0.f, 0.f);
    if (h < 256 && w < 256) {
        const float* wrow = &wlds[(h & 7) * 8 + (w & 7)];
        const float* gp   = inp + h * 256 + w;
#pragma unroll
        for (int t = 0; t < TT; ++t) {
            const float4 v  = *reinterpret_cast<const float4*>(gp + t * 65536);
            const float4 wv = *reinterpret_cast<const float4*>(wrow + t * 64);
            acc.x += v.x * wv.x;
            acc.y += v.y * wv.y;
            acc.z += v.z * wv.z;
            acc.w += v.w * wv.w;
        }
    }
    return acc;
}

// store two window-rows (di = d0, d0+1), 32 windows across 8 waves
__device__ __forceinline__ void store2(const float* __restrict__ tile,
                                       float* __restrict__ outb,
                                       int i0, int j0, int d0,
                                       int wave, int lane, int p0, int q)
{
#pragma unroll
    for (int m = 0; m < 4; ++m) {
        const int widx = wave + 8 * m;          // 0..31
        const int di = d0 + (widx >> 4);        // local window-row
        const int dj = widx & 15;
        const float* src = &tile[(di * 8 + p0) * LDSW + dj * 8 + q];
        const int n = (i0 + di) * 32 + (j0 + dj);
        store_nt(outb + (size_t)n * 256 + lane * 4,
                 src[0 * LDSW], src[1 * LDSW], src[2 * LDSW], src[3 * LDSW]);
    }
}

__global__ __launch_bounds__(512, 2) void meas_kernel(
    const float* __restrict__ in, const float* __restrict__ wt,
    float* __restrict__ out)
{
    __shared__ float tile[ROWS * LDSW];
    __shared__ float wlds[TT * 64];

    const int tid = threadIdx.x;
    for (int idx = tid; idx < TT * 64; idx += 512) wlds[idx] = wt[idx];

    // XCD swizzle: 256 blocks, 8 XCDs -> 32 logical blocks (one b, all s) per XCD.
    // Logical bits: b(5..7) | s(3..4) | ig(1..2) | jg(0) -> ig-neighbors share halo on-XCD.
    const int bid = (blockIdx.x & 7) * 32 + (blockIdx.x >> 3);
    const int jg = bid & 1;
    const int ig = (bid >> 1) & 3;
    const int s  = (bid >> 3) & 3;
    const int b  = bid >> 5;

    const int i0 = ig * 8;      // first window row
    const int j0 = jg * 16;     // first window col
    const int h0 = ig * 64;     // region row origin
    const int w0 = jg * 128;    // region col origin

    const float* __restrict__ inp = in + (size_t)(b * 4 + s) * TT * 65536;
    float* __restrict__ outb = out + ((size_t)b * 4096 + (size_t)s * 1024) * 256;

    // store-phase lane mapping: k = 4*lane + jj : p = 4*(lane%4) + jj, q = lane/4
    const int wave = tid >> 6;   // 0..7
    const int lane = tid & 63;
    const int p0 = (lane & 3) * 4;
    const int q  = lane >> 2;

    lds_barrier();   // weights visible

    // ---- S0: rows [0, 24) ----
    for (int slot = tid; slot < 24 * C4; slot += 512) {
        const int r  = slot / C4;
        const int c4 = slot - r * C4;
        const float4 acc = compute_slot(inp, wlds, h0, w0, r, c4);
        *reinterpret_cast<float4*>(&tile[r * LDSW + c4 * 4]) = acc;
    }
    lds_barrier();

    // ---- rolling sub-phases ----
    for (int k = 0; k < 3; ++k) {
        const int RB = 24 + 16 * k;

        // 1) issue loads for rows [RB, RB+16): 544 slots = 512 + 32 strays
        const int r0  = RB + tid / C4;
        const int c40 = tid - (tid / C4) * C4;
        float4 v0[TT];
        const bool ok0 = load16(v0, inp, h0 + r0, w0 + c40 * 4);

        const bool has1 = tid < (16 * C4 - 512);   // 32 threads
        const int st  = tid + 512;
        const int r1  = RB + st / C4;
        const int c41 = st - (st / C4) * C4;
        float4 v1[TT];
        bool ok1 = false;
        if (has1) ok1 = load16(v1, inp, h0 + r1, w0 + c41 * 4);

        // 2) store window-rows di = 2k, 2k+1 (needs LDS rows < RB, all committed)
        store2(tile, outb, i0, j0, 2 * k, wave, lane, p0, q);

        // 3) FMA + commit
        float4 a0 = make_float4(0.f, 0.f, 0.f, 0.f);
        if (ok0) a0 = dot16(v0, wlds, h0 + r0, w0 + c40 * 4);
        *reinterpret_cast<float4*>(&tile[r0 * LDSW + c40 * 4]) = a0;
        if (has1) {
            float4 a1 = make_float4(0.f, 0.f, 0.f, 0.f);
            if (ok1) a1 = dot16(v1, wlds, h0 + r1, w0 + c41 * 4);
            *reinterpret_cast<float4*>(&tile[r1 * LDSW + c41 * 4]) = a1;
        }

        lds_barrier();
    }

    // ---- final stores: window-rows 6, 7 ----
    store2(tile, outb, i0, j0, 6, wave, lane, p0, q);
}

} // namespace

extern "C" void kernel_launch(void* const* d_in, const int* in_sizes, int n_in,
                              void* d_out, int out_size, void* d_ws, size_t ws_size,
                              hipStream_t stream) {
    const float* in = (const float*)d_in[0];
    const float* wt = (const float*)d_in[1];
    float* out      = (float*)d_out;
    hipLaunchKernelGGL(meas_kernel, dim3(256), dim3(512), 0, stream, in, wt, out);
}

// Round 6
// 38.116 us; speedup vs baseline: 1.5074x; 1.5074x over previous
//
#include <hip/hip_runtime.h>

// out[b,s,h,w] = sum_t input[b,s,t,h,w] * weight[t, h%8, w%8]   (h,w < 256; else 0)
// output[b, s*1024 + i*32 + j, q*16 + p] = out[b,s, 8i+p, 8j+q]   i,j in [0,32), p,q in [0,16)
//
// Block = (b, s, ig, jg): windows i in [4*ig, 4*ig+4), j in [16*jg, 16*jg+16).
// Region rows [32*ig, 32*ig+40) x cols [128*jg, 128*jg+136).
//
// Round-6: identical to round-4 except nontemporal stores -> plain stores.
// R5 counters showed nt stores bypass L2 write-combining: WRITE_SIZE 86.4 MB
// for 33.5 MB of output (2.6x amplification).

namespace {

constexpr int TT    = 16;
constexpr int ROWS  = 40;   // 4*8 + 8 halo
constexpr int C4    = 34;   // float4 slots per row = 136 cols
constexpr int LDSW  = 140;  // row pitch (floats): float4-aligned rows, 2-way-max bank spread
constexpr int RSPLIT = 24;  // rows in stage P1a

__device__ __forceinline__ float4 compute_slot(
    const float* __restrict__ inp, const float* __restrict__ wlds,
    int h0, int w0, int r, int c4)
{
    const int h = h0 + r;
    const int w = w0 + c4 * 4;
    float4 acc = make_float4(0.f, 0.f, 0.f, 0.f);
    if (h < 256 && w < 256) {
        const float* wrow = &wlds[(h & 7) * 8 + (w & 7)];
        const float* gp   = inp + h * 256 + w;
#pragma unroll
        for (int t = 0; t < TT; ++t) {
            const float4 v  = *reinterpret_cast<const float4*>(gp + t * 65536);
            const float4 wv = *reinterpret_cast<const float4*>(wrow + t * 64);
            acc.x += v.x * wv.x;
            acc.y += v.y * wv.y;
            acc.z += v.z * wv.z;
            acc.w += v.w * wv.w;
        }
    }
    return acc;
}

__global__ __launch_bounds__(512, 4) void meas_kernel(
    const float* __restrict__ in, const float* __restrict__ wt,
    float* __restrict__ out)
{
    __shared__ float tile[ROWS * LDSW];
    __shared__ float wlds[TT * 64];

    const int tid = threadIdx.x;
    for (int idx = tid; idx < TT * 64; idx += 512) wlds[idx] = wt[idx];

    // XCD-aware swizzle: 512 blocks, 8 XCDs -> 64 logical blocks (one batch image) per XCD.
    const int bid = (blockIdx.x & 7) * 64 + (blockIdx.x >> 3);
    const int jg = bid & 1;
    const int ig = (bid >> 1) & 7;
    const int s  = (bid >> 4) & 3;
    const int b  = bid >> 6;

    const int i0 = ig * 4;
    const int j0 = jg * 16;
    const int h0 = i0 * 8;
    const int w0 = j0 * 8;

    const float* __restrict__ inp = in + (size_t)(b * 4 + s) * TT * 65536;

    // store-phase lane mapping: k = 4*lane + jj : p = 4*(lane%4) + jj, q = lane/4
    const int wave = tid >> 6;     // 0..7
    const int lane = tid & 63;
    const int p0 = (lane & 3) * 4;
    const int q  = lane >> 2;
    float* __restrict__ outb = out + ((size_t)b * 4096 + (size_t)s * 1024) * 256;

    __syncthreads();

    // ---- P1a: compute tile rows [0, 24) ----
    for (int slot = tid; slot < RSPLIT * C4; slot += 512) {
        const int r  = slot / C4;
        const int c4 = slot - r * C4;
        float4 acc = compute_slot(inp, wlds, h0, w0, r, c4);
        *reinterpret_cast<float4*>(&tile[r * LDSW + c4 * 4]) = acc;
    }

    __syncthreads();

    // ---- P1b: rows [24, 40) into registers (loads in flight during S01) ----
    constexpr int NB = (ROWS - RSPLIT) * C4;   // 544
    float4 acc0, acc1;
    int r0 = 0, c40 = 0, r1 = 0, c41 = 0;
    {
        const int slot = tid;                  // tid < 544 always (512 threads)
        r0  = RSPLIT + slot / C4;
        c40 = slot - (slot / C4) * C4;
        acc0 = compute_slot(inp, wlds, h0, w0, r0, c40);
    }
    const bool has1 = tid < (NB - 512);        // 32 threads
    if (has1) {
        const int slot = tid + 512;
        r1  = RSPLIT + slot / C4;
        c41 = slot - (slot / C4) * C4;
        acc1 = compute_slot(inp, wlds, h0, w0, r1, c41);
    }

    // ---- S01: store windows di = 0,1 (LDS rows 0..23) ----
    for (int widx = wave; widx < 32; widx += 8) {
        const int di = widx >> 4;   // 0..1
        const int dj = widx & 15;
        const float* src = &tile[(di * 8 + p0) * LDSW + dj * 8 + q];
        const int n = (i0 + di) * 32 + (j0 + dj);
        *reinterpret_cast<float4*>(outb + (size_t)n * 256 + lane * 4) =
            make_float4(src[0 * LDSW], src[1 * LDSW], src[2 * LDSW], src[3 * LDSW]);
    }

    // ---- commit P1b rows to LDS ----
    *reinterpret_cast<float4*>(&tile[r0 * LDSW + c40 * 4]) = acc0;
    if (has1)
        *reinterpret_cast<float4*>(&tile[r1 * LDSW + c41 * 4]) = acc1;

    __syncthreads();

    // ---- S23: store windows di = 2,3 ----
    for (int widx = 32 + wave; widx < 64; widx += 8) {
        const int di = widx >> 4;   // 2..3
        const int dj = widx & 15;
        const float* src = &tile[(di * 8 + p0) * LDSW + dj * 8 + q];
        const int n = (i0 + di) * 32 + (j0 + dj);
        *reinterpret_cast<float4*>(outb + (size_t)n * 256 + lane * 4) =
            make_float4(src[0 * LDSW], src[1 * LDSW], src[2 * LDSW], src[3 * LDSW]);
    }
}

} // namespace

extern "C" void kernel_launch(void* const* d_in, const int* in_sizes, int n_in,
                              void* d_out, int out_size, void* d_ws, size_t ws_size,
                              hipStream_t stream) {
    const float* in = (const float*)d_in[0];
    const float* wt = (const float*)d_in[1];
    float* out      = (float*)d_out;
    hipLaunchKernelGGL(meas_kernel, dim3(512), dim3(512), 0, stream, in, wt, out);
}